// Round 1
// baseline (934.134 us; speedup 1.0000x reference)
//
#include <hip/hip_runtime.h>

typedef _Float16 v8h __attribute__((ext_vector_type(8)));
typedef float    v4f __attribute__((ext_vector_type(4)));

#define ACT_OFF  131072              // LDS: weight blocks [0,131072)
#define ACT_SLOT 13056               // one act slot: 3 layers * 16 rows * 136 halfs
#define ACT_L    4352                // one layer within a slot: 16*272 bytes
#define BIAS_OFF (ACT_OFF + 2*ACT_SLOT)   // 157184, 3072 bytes fp16 bias
#define FC_OFF   (BIAS_OFF + 3072)        // 160256, 512 bytes fc frags
#define SMEM_SZ  (FC_OFF + 512)           // 160768 <= 163840
#define HWS_OFF  1048576              // byte offset of fp32 h-state in d_ws

__device__ __forceinline__ float sigm(float x) {
  return __builtin_amdgcn_rcpf(1.f + __expf(-x));
}
__device__ __forceinline__ float tanh_(float x) {
  return 1.f - 2.f * __builtin_amdgcn_rcpf(1.f + __expf(2.f * x));
}

// Convert fp32 weights into fp16 MFMA B-fragment image.
// Image: [wave 0..7][blk 0..71][lane 0..63] * 16B.
// Per layer, blk canonical order c: R k0..7 (k<4 = W_ih, k>=4 = W_hh),
// Z k0..7, Nx k0..3 (W_ih), Nh k0..3 (W_hh). blk = l*24 + c.
__global__ void prep_weights(const float* __restrict__ Wih,
                             const float* __restrict__ Whh,
                             _Float16* __restrict__ img) {
  int bid = blockIdx.x;              // 0..575
  int lane = threadIdx.x;            // 0..63
  int w = bid / 72, blk = bid % 72, l = blk / 24, c = blk % 24;
  int n = lane & 15, q = lane >> 4, h = w * 16 + n;
  int row, k0; const float* M;
  if (c < 16)      { int kk = c & 7; row = (c < 8 ? 0 : 128) + h;
                     M = (kk < 4 ? Wih : Whh); k0 = (kk & 3) * 32; }
  else if (c < 20) { row = 256 + h; M = Wih; k0 = (c - 16) * 32; }
  else             { row = 256 + h; M = Whh; k0 = (c - 20) * 32; }
  const float* src = M + l * 49152 + row * 128 + k0 + q * 8;
  _Float16* dst = img + (((long)bid) * 64 + lane) * 8;
  #pragma unroll
  for (int j = 0; j < 8; ++j) dst[j] = (_Float16)src[j];
}

__global__ __launch_bounds__(512, 2)
void gru_main(const float* __restrict__ hiddens, const float* __restrict__ bih,
              const float* __restrict__ bhh, const float* __restrict__ fcw,
              const float* __restrict__ fcb, const _Float16* __restrict__ img,
              float* __restrict__ hwsg, float* __restrict__ out) {
  extern __shared__ char smem[];
  const int tid = threadIdx.x, wg = blockIdx.x;
  const int lane = tid & 63, w = tid >> 6, col = lane & 15, q = lane >> 4;

  // ---- register-resident weight fragments (56 blocks = 224 VGPRs) ----
  // wr index: l<2: l*16 + c (c: R0-7 -> 0..7, Z0-7 -> 8..15); l==2: 32 + c (c 0..23)
  v8h wr[56];
  #pragma unroll
  for (int i = 0; i < 56; ++i) {
    int l = (i < 32) ? (i >> 4) : 2;
    int c = (i < 32) ? (i & 15) : (i - 32);
    int blk = l * 24 + c;
    wr[i] = *(const v8h*)(img + (((long)(w * 72 + blk)) * 64 + lane) * 8);
  }
  // ---- LDS-resident weight fragments: layers 0,1 Nx/Nh (16 blocks/wave) ----
  #pragma unroll
  for (int j = 0; j < 16; ++j) {
    int l = j >> 3, c = 16 + (j & 7), blk = l * 24 + c;
    *(v8h*)(smem + (w * 16 + j) * 1024 + lane * 16) =
        *(const v8h*)(img + (((long)(w * 72 + blk)) * 64 + lane) * 8);
  }
  // ---- act slot0 (fp16) + fp32 h-state init from hiddens [B][3][128] ----
  float* hws = hwsg + (long)wg * 6144;
  for (int i = tid; i < 6144; i += 512) {
    int l = i >> 11, b = (i >> 7) & 15, h = i & 127;
    float v = hiddens[((long)(wg * 16 + b) * 3 + l) * 128 + h];
    *(_Float16*)(smem + ACT_OFF + l * ACT_L + b * 272 + h * 2) = (_Float16)v;
    hws[(l * 128 + h) * 16 + b] = v;
  }
  // ---- biases (fp16): [l][w][tile R,Z,NX,NH][col] ----
  for (int i = tid; i < 1536; i += 512) {
    int l = i >> 9, rem = i & 511, w2 = rem >> 6, tile = (rem >> 4) & 3, cc = rem & 15;
    int h2 = w2 * 16 + cc;
    float bv;
    if      (tile == 0) bv = bih[l * 384 + h2]       + bhh[l * 384 + h2];
    else if (tile == 1) bv = bih[l * 384 + 128 + h2] + bhh[l * 384 + 128 + h2];
    else if (tile == 2) bv = bih[l * 384 + 256 + h2];
    else                bv = bhh[l * 384 + 256 + h2];
    *(_Float16*)(smem + BIAS_OFF + i * 2) = (_Float16)bv;
  }
  // ---- fc B-frags, compact: [k 0..3][col 0..1][q 0..3] * 16B ----
  if (tid < 32) {
    int k = tid >> 3, c2 = (tid >> 2) & 1, q2 = tid & 3;
    v8h f;
    #pragma unroll
    for (int j = 0; j < 8; ++j) f[j] = (_Float16)fcw[c2 * 128 + k * 32 + q2 * 8 + j];
    *(v8h*)(smem + FC_OFF + tid * 16) = f;
  }
  float myfcb = (w == 0 && col < 2) ? fcb[col] : 0.f;
  __syncthreads();

  // ---- pointers ----
  char* actbase = smem + ACT_OFF + col * 272 + q * 16;  // A-frag lane base (m=col)
  char* arp = actbase;                                  // read slot (slot 0 first)
  char* awr = actbase + ACT_SLOT;                       // write slot
  const int dEW = q * 1072 + w * 32 - col * 270;        // frag-base -> EW-write-base
  char* wldsp = smem + w * 16384 + lane * 16;
  const char* bp = smem + BIAS_OFF + w * 128 + col * 2;
  const int hoffe = (w * 16 + col) * 16 + q * 4;

  #pragma unroll 1
  for (int t = 0; t < 256; ++t) {
    #pragma unroll
    for (int l = 0; l < 3; ++l) {
      v4f hold = *(const v4f*)(hws + l * 2048 + hoffe);
      float bR  = (float)*(const _Float16*)(bp + l * 1024);
      float bZ  = (float)*(const _Float16*)(bp + l * 1024 + 32);
      float bNX = (float)*(const _Float16*)(bp + l * 1024 + 64);
      float bNH = (float)*(const _Float16*)(bp + l * 1024 + 96);
      v4f aR  = {bR, bR, bR, bR};
      v4f aZ  = {bZ, bZ, bZ, bZ};
      v4f aNX = {bNX, bNX, bNX, bNX};
      v4f aNH = {bNH, bNH, bNH, bNH};
      // x side (x of layer0 = top output of prev step; zero at t==0)
      if (l > 0 || t > 0) {
        const char* xb = (l == 0) ? arp : awr;
        const int xl = (l == 0) ? 2 : l - 1;
        #pragma unroll
        for (int k = 0; k < 4; ++k) {
          v8h xa = *(const v8h*)(xb + xl * ACT_L + k * 64);
          aR = __builtin_amdgcn_mfma_f32_16x16x32_f16(xa, wr[(l < 2 ? l * 16 : 32) + k], aR, 0, 0, 0);
          aZ = __builtin_amdgcn_mfma_f32_16x16x32_f16(xa, wr[(l < 2 ? l * 16 : 32) + 8 + k], aZ, 0, 0, 0);
          v8h wnx = (l < 2) ? *(const v8h*)(wldsp + (l * 8 + k) * 1024) : wr[48 + k];
          aNX = __builtin_amdgcn_mfma_f32_16x16x32_f16(xa, wnx, aNX, 0, 0, 0);
        }
      }
      // h side
      #pragma unroll
      for (int k = 0; k < 4; ++k) {
        v8h ha = *(const v8h*)(arp + l * ACT_L + k * 64);
        aR = __builtin_amdgcn_mfma_f32_16x16x32_f16(ha, wr[(l < 2 ? l * 16 : 32) + 4 + k], aR, 0, 0, 0);
        aZ = __builtin_amdgcn_mfma_f32_16x16x32_f16(ha, wr[(l < 2 ? l * 16 : 32) + 12 + k], aZ, 0, 0, 0);
        v8h wnh = (l < 2) ? *(const v8h*)(wldsp + (l * 8 + 4 + k) * 1024) : wr[52 + k];
        aNH = __builtin_amdgcn_mfma_f32_16x16x32_f16(ha, wnh, aNH, 0, 0, 0);
      }
      // elementwise gates (fp32), write fp16 act + fp32 h-state
      v4f hn;
      #pragma unroll
      for (int r = 0; r < 4; ++r) {
        float rg = sigm(aR[r]);
        float zg = sigm(aZ[r]);
        float ng = tanh_(aNX[r] + rg * aNH[r]);
        hn[r] = ng + zg * (hold[r] - ng);
        *(_Float16*)(awr + dEW + l * ACT_L + r * 272) = (_Float16)hn[r];
      }
      *(v4f*)(hws + l * 2048 + hoffe) = hn;
      __syncthreads();
    }
    // FC epilogue: wave 0 only, out[b][t][o] = fc_w @ h2' + fc_b
    if (w == 0) {
      v4f d = {0.f, 0.f, 0.f, 0.f};
      #pragma unroll
      for (int k = 0; k < 4; ++k) {
        v8h xa = *(const v8h*)(awr + 2 * ACT_L + k * 64);
        v8h fw = {};
        if (col < 2) fw = *(const v8h*)(smem + FC_OFF + ((k * 2 + col) * 4 + q) * 16);
        d = __builtin_amdgcn_mfma_f32_16x16x32_f16(xa, fw, d, 0, 0, 0);
      }
      if (col < 2) {
        #pragma unroll
        for (int r = 0; r < 4; ++r)
          out[((long)(wg * 16 + q * 4 + r) * 256 + t) * 2 + col] = d[r] + myfcb;
      }
    }
    // swap act slots
    char* tmp = arp; arp = awr; awr = tmp;
  }
}

extern "C" void kernel_launch(void* const* d_in, const int* in_sizes, int n_in,
                              void* d_out, int out_size, void* d_ws, size_t ws_size,
                              hipStream_t stream) {
  (void)in_sizes; (void)n_in; (void)out_size; (void)ws_size;
  const float* hiddens = (const float*)d_in[0];
  const float* Wih     = (const float*)d_in[1];
  const float* Whh     = (const float*)d_in[2];
  const float* bih     = (const float*)d_in[3];
  const float* bhh     = (const float*)d_in[4];
  const float* fcw     = (const float*)d_in[5];
  const float* fcb     = (const float*)d_in[6];
  _Float16* img = (_Float16*)d_ws;
  float* hws = (float*)((char*)d_ws + HWS_OFF);
  float* out = (float*)d_out;

  // >64KB dynamic LDS opt-in (idempotent; capture-safe host call)
  hipFuncSetAttribute(reinterpret_cast<const void*>(gru_main),
                      hipFuncAttributeMaxDynamicSharedMemorySize, SMEM_SZ);

  prep_weights<<<576, 64, 0, stream>>>(Wih, Whh, img);
  gru_main<<<64, 512, SMEM_SZ, stream>>>(hiddens, bih, bhh, fcw, fcb, img, hws, out);
}

// Round 2
// 884.944 us; speedup vs baseline: 1.0556x; 1.0556x over previous
//
#include <hip/hip_runtime.h>
#include <stdint.h>

typedef int   v4i __attribute__((ext_vector_type(4)));
typedef float v4f __attribute__((ext_vector_type(4)));

// LDS map: [0,65536)          i8 weight frags, [wave][j 0..7][lane][16B]
//          [65536, +2*13824)  act slots (hi: [l][row16][144B], lo at +6912)
//          FC_OFF             fc i8 B-frags, 2 blocks of 1KB
#define ACT_OFF  65536
#define SLOT_SZ  13824
#define LO_OFF   6912
#define FC_OFF   (ACT_OFF + 2*SLOT_SZ)   // 93184
#define SMEM_SZ  (FC_OFF + 2048)         // 95232 (>64K: needs opt-in)

#define QW   1436.84056f      // 127/s, s = 1/sqrt(128)
#define C1f  4.38394754e-5f   // s*8/127^2  (hi-accum scale)
#define C2f  3.45193507e-7f   // C1/127     (lo-accum scale)

__device__ __forceinline__ float sigm(float x) {
  return __builtin_amdgcn_rcpf(1.f + __expf(-x));
}
__device__ __forceinline__ float tanh_(float x) {
  return 1.f - 2.f * __builtin_amdgcn_rcpf(1.f + __expf(2.f * x));
}

// i8 weight image: blk = l*12 + o*2 + kh, o: 0 Rx,1 Rh,2 Zx,3 Zh,4 Nx,5 Nh.
// B-frag: lane(col=lane&15=out, q=lane>>4) holds k = kh*64 + q*16 + j, j=0..15.
__global__ void prep_weights(const float* __restrict__ Wih,
                             const float* __restrict__ Whh,
                             int8_t* __restrict__ img) {
  int bid = blockIdx.x, lane = threadIdx.x;          // 288 blocks x 64
  int w = bid / 36, blk = bid % 36;
  int l = blk / 12, rem = blk % 12, o = rem >> 1, kh = rem & 1;
  const float* M = (o & 1) ? Whh : Wih;
  int row = (o >> 1) * 128 + w * 16 + (lane & 15);
  int k0 = kh * 64 + (lane >> 4) * 16;
  const float* src = M + l * 49152 + row * 128 + k0;
  int words[4];
  #pragma unroll
  for (int j4 = 0; j4 < 4; ++j4) {
    unsigned wd = 0;
    #pragma unroll
    for (int j = 0; j < 4; ++j) {
      int q = (int)rintf(src[j4 * 4 + j] * QW);
      wd |= ((unsigned)(q & 255)) << (8 * j);
    }
    words[j4] = (int)wd;
  }
  *(v4i*)(img + (((long)bid) * 64 + lane) * 16) = *(const v4i*)words;
}

__global__ __launch_bounds__(512, 2)
void gru_main(const float* __restrict__ hiddens, const float* __restrict__ bih,
              const float* __restrict__ bhh, const float* __restrict__ fcw,
              const float* __restrict__ fcb, const int8_t* __restrict__ img,
              float* __restrict__ out) {
  extern __shared__ char smem[];
  const int tid = threadIdx.x, wg = blockIdx.x;
  const int lane = tid & 63, w = tid >> 6, col = lane & 15, q = lane >> 4;
  const int hid = w * 16 + col;

  // ---- register weight frags (28 x 16B = 112 VGPRs) ----
  // idx<24: l*8 + o*2 + kh (o 0..3); idx 24..27: layer2 Nx(24,25)/Nh(26,27)
  v4i wr[28];
  #pragma unroll
  for (int i = 0; i < 28; ++i) {
    int blk = (i < 24) ? ((i >> 3) * 12 + (i & 7)) : (i + 8);
    wr[i] = *(const v4i*)(img + (((long)(w * 36 + blk)) * 64 + lane) * 16);
  }
  // ---- LDS weight frags: Nx/Nh of layers 0,1 (j = l*4 + oo*2 + kh) ----
  #pragma unroll
  for (int j = 0; j < 8; ++j) {
    int blk = (j >> 2) * 12 + 8 + (j & 3);
    *(v4i*)(smem + w * 8192 + j * 1024 + lane * 16) =
        *(const v4i*)(img + (((long)(w * 36 + blk)) * 64 + lane) * 16);
  }
  // ---- fc i8 B-frags in LDS (2 blocks; cols>=2 zero) ----
  if (tid < 128) {
    int kh = tid >> 6, ln = tid & 63, c2 = ln & 15, q2 = ln >> 4;
    int words[4] = {0, 0, 0, 0};
    if (c2 < 2) {
      const float* src = fcw + c2 * 128 + kh * 64 + q2 * 16;
      #pragma unroll
      for (int j4 = 0; j4 < 4; ++j4) {
        unsigned wd = 0;
        #pragma unroll
        for (int j = 0; j < 4; ++j) {
          int qv = (int)rintf(src[j4 * 4 + j] * QW);
          wd |= ((unsigned)(qv & 255)) << (8 * j);
        }
        words[j4] = (int)wd;
      }
    }
    *(v4i*)(smem + FC_OFF + kh * 1024 + ln * 16) = *(const v4i*)words;
  }
  // ---- biases (12 regs), fp32 h-state (12 regs), act slot0 init ----
  float bR[3], bZ[3], bNX[3], bNH[3];
  v4f hst[3];
  #pragma unroll
  for (int l = 0; l < 3; ++l) {
    bR[l]  = bih[l * 384 + hid]       + bhh[l * 384 + hid];
    bZ[l]  = bih[l * 384 + 128 + hid] + bhh[l * 384 + 128 + hid];
    bNX[l] = bih[l * 384 + 256 + hid];
    bNH[l] = bhh[l * 384 + 256 + hid];
    int8_t* ew0 = (int8_t*)(smem + ACT_OFF + l * 2304 + q * 576 + hid);
    #pragma unroll
    for (int r = 0; r < 4; ++r) {
      float v = hiddens[((long)(wg * 16 + q * 4 + r)) * 384 + l * 128 + hid];
      hst[l][r] = v;
      float f = v * 15.875f, fhi = rintf(f);
      ew0[r * 144]          = (int8_t)(int)fhi;
      ew0[r * 144 + LO_OFF] = (int8_t)(int)rintf((f - fhi) * 127.0f);
    }
  }
  float myfcb = (w == 0 && col < 2) ? fcb[col] : 0.f;
  __syncthreads();

  const char* fragb = smem + ACT_OFF + col * 144 + q * 16;  // A-frag lane base
  char* ewb = smem + ACT_OFF + q * 576 + hid;               // EW write lane base

  #pragma unroll 1
  for (int t = 0; t < 256; ++t) {
    const int so = (t & 1) * SLOT_SZ;          // read slot offset
    const int sn = SLOT_SZ - so;               // write slot offset
    #pragma unroll
    for (int l = 0; l < 3; ++l) {
      v4i aRh = {0,0,0,0}, aRl = {0,0,0,0}, aZh = {0,0,0,0}, aZl = {0,0,0,0};
      v4i aXh = {0,0,0,0}, aXl = {0,0,0,0}, aHh = {0,0,0,0}, aHl = {0,0,0,0};
      // x side: l==0 reads prev-step layer2 (read slot); l>0 reads write slot
      if (l > 0 || t > 0) {
        const char* xp = fragb + ((l == 0) ? (so + 2 * 2304) : (sn + (l - 1) * 2304));
        #pragma unroll
        for (int kh = 0; kh < 2; ++kh) {
          v4i xh = *(const v4i*)(xp + kh * 64);
          v4i xl = *(const v4i*)(xp + kh * 64 + LO_OFF);
          v4i wrx = wr[(l < 2 ? l * 8 : 16) + kh];
          v4i wzx = wr[(l < 2 ? l * 8 : 16) + 4 + kh];
          v4i wnx = (l < 2) ? *(const v4i*)(smem + w * 8192 + (l * 4 + kh) * 1024 + lane * 16)
                            : wr[24 + kh];
          aRh = __builtin_amdgcn_mfma_i32_16x16x64_i8(xh, wrx, aRh, 0, 0, 0);
          aRl = __builtin_amdgcn_mfma_i32_16x16x64_i8(xl, wrx, aRl, 0, 0, 0);
          aZh = __builtin_amdgcn_mfma_i32_16x16x64_i8(xh, wzx, aZh, 0, 0, 0);
          aZl = __builtin_amdgcn_mfma_i32_16x16x64_i8(xl, wzx, aZl, 0, 0, 0);
          aXh = __builtin_amdgcn_mfma_i32_16x16x64_i8(xh, wnx, aXh, 0, 0, 0);
          aXl = __builtin_amdgcn_mfma_i32_16x16x64_i8(xl, wnx, aXl, 0, 0, 0);
        }
      }
      // h side: read slot, layer l
      {
        const char* hp = fragb + so + l * 2304;
        #pragma unroll
        for (int kh = 0; kh < 2; ++kh) {
          v4i hh = *(const v4i*)(hp + kh * 64);
          v4i hl = *(const v4i*)(hp + kh * 64 + LO_OFF);
          v4i wrh = wr[(l < 2 ? l * 8 : 16) + 2 + kh];
          v4i wzh = wr[(l < 2 ? l * 8 : 16) + 6 + kh];
          v4i wnh = (l < 2) ? *(const v4i*)(smem + w * 8192 + (l * 4 + 2 + kh) * 1024 + lane * 16)
                            : wr[26 + kh];
          aRh = __builtin_amdgcn_mfma_i32_16x16x64_i8(hh, wrh, aRh, 0, 0, 0);
          aRl = __builtin_amdgcn_mfma_i32_16x16x64_i8(hl, wrh, aRl, 0, 0, 0);
          aZh = __builtin_amdgcn_mfma_i32_16x16x64_i8(hh, wzh, aZh, 0, 0, 0);
          aZl = __builtin_amdgcn_mfma_i32_16x16x64_i8(hl, wzh, aZl, 0, 0, 0);
          aHh = __builtin_amdgcn_mfma_i32_16x16x64_i8(hh, wnh, aHh, 0, 0, 0);
          aHl = __builtin_amdgcn_mfma_i32_16x16x64_i8(hl, wnh, aHl, 0, 0, 0);
        }
      }
      // elementwise (fp32 exact state), write hi/lo i8 acts to write slot
      int8_t* ew = (int8_t*)(ewb + sn + l * 2304);
      #pragma unroll
      for (int r = 0; r < 4; ++r) {
        float gR = bR[l] + C1f * (float)aRh[r] + C2f * (float)aRl[r];
        float gZ = bZ[l] + C1f * (float)aZh[r] + C2f * (float)aZl[r];
        float gX = bNX[l] + C1f * (float)aXh[r] + C2f * (float)aXl[r];
        float gH = bNH[l] + C1f * (float)aHh[r] + C2f * (float)aHl[r];
        float rg = sigm(gR), zg = sigm(gZ);
        float ng = tanh_(gX + rg * gH);
        float hn = ng + zg * (hst[l][r] - ng);
        hst[l][r] = hn;
        float f = hn * 15.875f, fhi = rintf(f);
        ew[r * 144]          = (int8_t)(int)fhi;
        ew[r * 144 + LO_OFF] = (int8_t)(int)rintf((f - fhi) * 127.0f);
      }
      __syncthreads();
    }
    // FC epilogue on wave 0: reads layer-2 acts just written (write slot)
    if (w == 0) {
      v4i dh = {0,0,0,0}, dl = {0,0,0,0};
      const char* xp = fragb + sn + 2 * 2304;
      #pragma unroll
      for (int kh = 0; kh < 2; ++kh) {
        v4i xh = *(const v4i*)(xp + kh * 64);
        v4i xl = *(const v4i*)(xp + kh * 64 + LO_OFF);
        v4i fw = *(const v4i*)(smem + FC_OFF + kh * 1024 + lane * 16);
        dh = __builtin_amdgcn_mfma_i32_16x16x64_i8(xh, fw, dh, 0, 0, 0);
        dl = __builtin_amdgcn_mfma_i32_16x16x64_i8(xl, fw, dl, 0, 0, 0);
      }
      if (col < 2) {
        #pragma unroll
        for (int r = 0; r < 4; ++r)
          out[((long)(wg * 16 + q * 4 + r) * 256 + t) * 2 + col] =
              myfcb + C1f * (float)dh[r] + C2f * (float)dl[r];
      }
    }
  }
}

extern "C" void kernel_launch(void* const* d_in, const int* in_sizes, int n_in,
                              void* d_out, int out_size, void* d_ws, size_t ws_size,
                              hipStream_t stream) {
  (void)in_sizes; (void)n_in; (void)out_size; (void)ws_size;
  const float* hiddens = (const float*)d_in[0];
  const float* Wih     = (const float*)d_in[1];
  const float* Whh     = (const float*)d_in[2];
  const float* bih     = (const float*)d_in[3];
  const float* bhh     = (const float*)d_in[4];
  const float* fcw     = (const float*)d_in[5];
  const float* fcb     = (const float*)d_in[6];
  int8_t* img = (int8_t*)d_ws;   // 288 KB weight image
  float* out = (float*)d_out;

  hipFuncSetAttribute(reinterpret_cast<const void*>(gru_main),
                      hipFuncAttributeMaxDynamicSharedMemorySize, SMEM_SZ);

  prep_weights<<<288, 64, 0, stream>>>(Wih, Whh, img);
  gru_main<<<64, 512, SMEM_SZ, stream>>>(hiddens, bih, bhh, fcw, fcb, img, out);
}